// Round 3
// baseline (96.095 us; speedup 1.0000x reference)
//
#include <hip/hip_runtime.h>
#include <math.h>

__device__ __forceinline__ float silu_act(float y) {
    return y / (1.f + __expf(-y));
}

// Pointwise 1x1 conv + scale/bias + SiLU. Compile-time Cin for full unroll.
template<int TC, int CIN>
__global__ void pw_conv_silu(const float* __restrict__ in, int HW, int B,
                             const float* __restrict__ w,
                             const float* __restrict__ sc, const float* __restrict__ bi,
                             float* __restrict__ out, int CoutStride) {
    int g = blockIdx.x * blockDim.x + threadIdx.x;
    if (g >= B * HW) return;
    int b = g / HW, pix = g - b * HW;
    int co0 = blockIdx.y * TC;
    float acc[TC];
#pragma unroll
    for (int j = 0; j < TC; ++j) acc[j] = 0.f;
    const float* ip = in + (size_t)b * CIN * HW + pix;
    const float* wp = w + (size_t)co0 * CIN;
#pragma unroll 8
    for (int ci = 0; ci < CIN; ++ci) {
        float v = ip[(size_t)ci * HW];
#pragma unroll
        for (int j = 0; j < TC; ++j)
            acc[j] = fmaf(v, wp[j * CIN + ci], acc[j]);
    }
#pragma unroll
    for (int j = 0; j < TC; ++j) {
        int co = co0 + j;
        float y = fmaf(acc[j], sc[co], bi[co]);
        out[((size_t)b * CoutStride + co) * HW + pix] = silu_act(y);
    }
}

// Fused depthwise 3x3 (channels [0,ch)) and 5x5 (channels [ch,2ch)) + SiLU.
__global__ void dw_conv_silu(float* __restrict__ cat, int ch, int H, int W, int Ctot, int B,
                             const float* __restrict__ w3, const float* __restrict__ s3,
                             const float* __restrict__ b3,
                             const float* __restrict__ w5, const float* __restrict__ s5,
                             const float* __restrict__ b5) {
    int HW = H * W;
    int idx = blockIdx.x * blockDim.x + threadIdx.x;
    int total = B * 2 * ch * HW;
    if (idx >= total) return;
    int pix = idx % HW;
    int t = idx / HW;
    int c2 = t % (2 * ch);
    int b = t / (2 * ch);
    int x = pix % W, y = pix / W;
    const float* ip = cat + ((size_t)b * Ctot + c2) * HW;
    float acc = 0.f, scale, bias;
    if (c2 < ch) {
        const float* wk = w3 + c2 * 9;
#pragma unroll
        for (int ky = 0; ky < 3; ++ky) {
            int iy = y + ky - 1;
            if ((unsigned)iy >= (unsigned)H) continue;
#pragma unroll
            for (int kx = 0; kx < 3; ++kx) {
                int ix = x + kx - 1;
                if ((unsigned)ix >= (unsigned)W) continue;
                acc = fmaf(ip[iy * W + ix], wk[ky * 3 + kx], acc);
            }
        }
        scale = s3[c2]; bias = b3[c2];
    } else {
        int c = c2 - ch;
        const float* wk = w5 + c * 25;
#pragma unroll
        for (int ky = 0; ky < 5; ++ky) {
            int iy = y + ky - 2;
            if ((unsigned)iy >= (unsigned)H) continue;
#pragma unroll
            for (int kx = 0; kx < 5; ++kx) {
                int ix = x + kx - 2;
                if ((unsigned)ix >= (unsigned)W) continue;
                acc = fmaf(ip[iy * W + ix], wk[ky * 5 + kx], acc);
            }
        }
        scale = s5[c]; bias = b5[c];
    }
    float v = fmaf(acc, scale, bias);
    cat[((size_t)b * Ctot + 2 * ch + c2) * HW + pix] = silu_act(v);
}

// Weight-prep: fuses enc_px (1x1 conv over 100ch + BN + SiLU), pixel-shuffle
// gather, and softmax over the 25 taps. Writes ws[b][Y][rp(4)][j(25)][l(64)].
// Block = (Y, b), 256 threads: t -> l = t&63 (input col), g = t>>6 = rp
// (wave-uniform). Thread computes the 25 channels co = j*4+g at pixel (Y,l).
__global__ __launch_bounds__(256) void wprep_kernel(
        const float* __restrict__ cat_e, const float* __restrict__ w,
        const float* __restrict__ sc, const float* __restrict__ bi,
        float* __restrict__ ws) {
    const int HW = 4096;
    int Y = blockIdx.x;
    int b = blockIdx.y;
    __shared__ float le[100][64];
    int t = threadIdx.x;
    // stage cat_e[b][*][Y][*]
    const float* src = cat_e + (size_t)b * 100 * HW + Y * 64;
    for (int i = t; i < 100 * 64; i += 256) {
        int ci = i >> 6, x = i & 63;
        le[ci][x] = src[(size_t)ci * HW + x];
    }
    __syncthreads();
    int l = t & 63;
    int g = __builtin_amdgcn_readfirstlane(t >> 6);   // rp, wave-uniform
    float xr[100];
#pragma unroll
    for (int ci = 0; ci < 100; ++ci) xr[ci] = le[ci][l];
    float acc[25];
#pragma unroll
    for (int j = 0; j < 25; ++j) acc[j] = 0.f;
#pragma unroll 4
    for (int ci = 0; ci < 100; ++ci) {
        float xv = xr[ci];
#pragma unroll
        for (int j = 0; j < 25; ++j)
            acc[j] = fmaf(xv, w[(j * 4 + g) * 100 + ci], acc[j]);
    }
    // BN + SiLU, then softmax over j
    float m = -1e30f;
#pragma unroll
    for (int j = 0; j < 25; ++j) {
        int co = j * 4 + g;
        acc[j] = silu_act(fmaf(acc[j], sc[co], bi[co]));
        m = fmaxf(m, acc[j]);
    }
    float s = 0.f;
#pragma unroll
    for (int j = 0; j < 25; ++j) { acc[j] = __expf(acc[j] - m); s += acc[j]; }
    float inv = 1.f / s;
    float* dst = ws + ((((size_t)b * 64 + Y) * 4 + g) * 25) * 64 + l;
#pragma unroll
    for (int j = 0; j < 25; ++j) dst[j * 64] = acc[j] * inv;
}

// CARAFE v3: weights in registers, zero-padded X tile in LDS, high occupancy.
// Block = (Y, 16-ch chunk, b); thread = (l = t&63, tc = t>>6); each thread
// computes 4 channels x 2x2 outputs at (oy=2Y+r, ox=2l+par).
__global__ __launch_bounds__(256) void carafe_kernel(
        const float* __restrict__ X, const float* __restrict__ ws,
        float* __restrict__ out) {
    const int H = 64, Wd = 64, C = 128, Ho = 128, Wo = 128, HW = H * Wd;
    int Y = blockIdx.x;           // 0..63
    int cchunk = blockIdx.y;      // 0..7
    int b = blockIdx.z;
    __shared__ float xs[16][5][68];     // zero-padded cols: col = ix+2, 21.8 KB
    int t = threadIdx.x;
    int c0 = cchunk * 16;
    const float* Xb = X + ((size_t)b * C + c0) * HW;
    for (int i = t; i < 16 * 5 * 68; i += 256) {
        int col = i % 68;
        int tmp = i / 68;
        int p = tmp % 5;
        int c = tmp / 5;
        int iy = Y + p - 2;
        int ix = col - 2;
        float v = 0.f;
        if ((unsigned)iy < (unsigned)H && (unsigned)ix < (unsigned)Wd)
            v = Xb[(size_t)c * HW + iy * Wd + ix];
        xs[c][p][col] = v;
    }
    // load this thread's 100 softmaxed weights (coalesced, reused 4 channels)
    int l = t & 63;
    int tc = t >> 6;
    const float* wsrow = ws + (((size_t)b * 64 + Y) * 100) * 64 + l;
    float wreg[4][25];
#pragma unroll
    for (int rp = 0; rp < 4; ++rp)
#pragma unroll
        for (int j = 0; j < 25; ++j)
            wreg[rp][j] = wsrow[(rp * 25 + j) * 64];
    __syncthreads();

#pragma unroll
    for (int k = 0; k < 4; ++k) {
        int c = tc * 4 + k;
        float a00 = 0.f, a01 = 0.f, a10 = 0.f, a11 = 0.f;
#pragma unroll
        for (int p = 0; p < 5; ++p)
#pragma unroll
            for (int q = 0; q < 5; ++q) {
                float v = xs[c][p][l + q];
                int j = p * 5 + q;
                a00 = fmaf(wreg[0][j], v, a00);
                a01 = fmaf(wreg[1][j], v, a01);
                a10 = fmaf(wreg[2][j], v, a10);
                a11 = fmaf(wreg[3][j], v, a11);
            }
        size_t ob = (((size_t)b * C + (c0 + c)) * Ho + 2 * Y) * Wo + 2 * l;
        *reinterpret_cast<float2*>(&out[ob])      = make_float2(a00, a01);
        *reinterpret_cast<float2*>(&out[ob + Wo]) = make_float2(a10, a11);
    }
}

extern "C" void kernel_launch(void* const* d_in, const int* in_sizes, int n_in,
                              void* d_out, int out_size, void* d_ws, size_t ws_size,
                              hipStream_t stream) {
    const float* X          = (const float*)d_in[0];
    const float* comp_cv1_w = (const float*)d_in[1];
    const float* comp_cv1_s = (const float*)d_in[2];
    const float* comp_cv1_b = (const float*)d_in[3];
    const float* comp_dw3_w = (const float*)d_in[4];
    const float* comp_dw3_s = (const float*)d_in[5];
    const float* comp_dw3_b = (const float*)d_in[6];
    const float* comp_dw5_w = (const float*)d_in[7];
    const float* comp_dw5_s = (const float*)d_in[8];
    const float* comp_dw5_b = (const float*)d_in[9];
    const float* comp_px_w  = (const float*)d_in[10];
    const float* comp_px_s  = (const float*)d_in[11];
    const float* comp_px_b  = (const float*)d_in[12];
    const float* enc_cv1_w  = (const float*)d_in[13];
    const float* enc_cv1_s  = (const float*)d_in[14];
    const float* enc_cv1_b  = (const float*)d_in[15];
    const float* enc_dw3_w  = (const float*)d_in[16];
    const float* enc_dw3_s  = (const float*)d_in[17];
    const float* enc_dw3_b  = (const float*)d_in[18];
    const float* enc_dw5_w  = (const float*)d_in[19];
    const float* enc_dw5_s  = (const float*)d_in[20];
    const float* enc_dw5_b  = (const float*)d_in[21];
    const float* enc_px_w   = (const float*)d_in[22];
    const float* enc_px_s   = (const float*)d_in[23];
    const float* enc_px_b   = (const float*)d_in[24];
    float* out = (float*)d_out;

    const int B = 2, H = 64, W = 64, HW = H * W;
    float* cat_c  = (float*)d_ws;                      // [B, 64, HW]
    float* y_comp = cat_c  + (size_t)B * 64 * HW;      // [B, 64, HW]
    float* cat_e  = y_comp + (size_t)B * 64 * HW;      // [B,100, HW]
    float* ws     = cat_e  + (size_t)B * 100 * HW;     // [B,64,4,25,64]

    int pixBlocks = (B * HW + 255) / 256;   // 32

    // comp MSGConv
    pw_conv_silu<4, 128><<<dim3(pixBlocks, 8), 256, 0, stream>>>(
        X, HW, B, comp_cv1_w, comp_cv1_s, comp_cv1_b, cat_c, 64);
    {
        int n = B * 32 * HW;
        dw_conv_silu<<<(n + 255) / 256, 256, 0, stream>>>(
            cat_c, 16, H, W, 64, B,
            comp_dw3_w, comp_dw3_s, comp_dw3_b,
            comp_dw5_w, comp_dw5_s, comp_dw5_b);
    }
    pw_conv_silu<4, 64><<<dim3(pixBlocks, 16), 256, 0, stream>>>(
        cat_c, HW, B, comp_px_w, comp_px_s, comp_px_b, y_comp, 64);

    // enc MSGConv (cv1 + dw); px is fused into wprep
    pw_conv_silu<5, 64><<<dim3(pixBlocks, 10), 256, 0, stream>>>(
        y_comp, HW, B, enc_cv1_w, enc_cv1_s, enc_cv1_b, cat_e, 100);
    {
        int n = B * 50 * HW;
        dw_conv_silu<<<(n + 255) / 256, 256, 0, stream>>>(
            cat_e, 25, H, W, 100, B,
            enc_dw3_w, enc_dw3_s, enc_dw3_b,
            enc_dw5_w, enc_dw5_s, enc_dw5_b);
    }

    // enc_px + softmax + pixel-shuffle transpose
    wprep_kernel<<<dim3(64, B), 256, 0, stream>>>(
        cat_e, enc_px_w, enc_px_s, enc_px_b, ws);

    // CARAFE reassembly
    carafe_kernel<<<dim3(64, 8, B), 256, 0, stream>>>(X, ws, out);
}

// Round 4
// 78.854 us; speedup vs baseline: 1.2186x; 1.2186x over previous
//
#include <hip/hip_runtime.h>
#include <math.h>

__device__ __forceinline__ float silu_act(float y) {
    return y / (1.f + __expf(-y));
}

// Pointwise 1x1 conv + scale/bias + SiLU. Compile-time Cin for full unroll.
template<int TC, int CIN>
__global__ void pw_conv_silu(const float* __restrict__ in, int HW, int B,
                             const float* __restrict__ w,
                             const float* __restrict__ sc, const float* __restrict__ bi,
                             float* __restrict__ out, int CoutStride) {
    int g = blockIdx.x * blockDim.x + threadIdx.x;
    if (g >= B * HW) return;
    int b = g / HW, pix = g - b * HW;
    int co0 = blockIdx.y * TC;
    float acc[TC];
#pragma unroll
    for (int j = 0; j < TC; ++j) acc[j] = 0.f;
    const float* ip = in + (size_t)b * CIN * HW + pix;
    const float* wp = w + (size_t)co0 * CIN;
#pragma unroll 8
    for (int ci = 0; ci < CIN; ++ci) {
        float v = ip[(size_t)ci * HW];
#pragma unroll
        for (int j = 0; j < TC; ++j)
            acc[j] = fmaf(v, wp[j * CIN + ci], acc[j]);
    }
#pragma unroll
    for (int j = 0; j < TC; ++j) {
        int co = co0 + j;
        float y = fmaf(acc[j], sc[co], bi[co]);
        out[((size_t)b * CoutStride + co) * HW + pix] = silu_act(y);
    }
}

// Fused depthwise 3x3 (channels [0,ch)) and 5x5 (channels [ch,2ch)) + SiLU.
__global__ void dw_conv_silu(float* __restrict__ cat, int ch, int H, int W, int Ctot, int B,
                             const float* __restrict__ w3, const float* __restrict__ s3,
                             const float* __restrict__ b3,
                             const float* __restrict__ w5, const float* __restrict__ s5,
                             const float* __restrict__ b5) {
    int HW = H * W;
    int idx = blockIdx.x * blockDim.x + threadIdx.x;
    int total = B * 2 * ch * HW;
    if (idx >= total) return;
    int pix = idx % HW;
    int t = idx / HW;
    int c2 = t % (2 * ch);
    int b = t / (2 * ch);
    int x = pix % W, y = pix / W;
    const float* ip = cat + ((size_t)b * Ctot + c2) * HW;
    float acc = 0.f, scale, bias;
    if (c2 < ch) {
        const float* wk = w3 + c2 * 9;
#pragma unroll
        for (int ky = 0; ky < 3; ++ky) {
            int iy = y + ky - 1;
            if ((unsigned)iy >= (unsigned)H) continue;
#pragma unroll
            for (int kx = 0; kx < 3; ++kx) {
                int ix = x + kx - 1;
                if ((unsigned)ix >= (unsigned)W) continue;
                acc = fmaf(ip[iy * W + ix], wk[ky * 3 + kx], acc);
            }
        }
        scale = s3[c2]; bias = b3[c2];
    } else {
        int c = c2 - ch;
        const float* wk = w5 + c * 25;
#pragma unroll
        for (int ky = 0; ky < 5; ++ky) {
            int iy = y + ky - 2;
            if ((unsigned)iy >= (unsigned)H) continue;
#pragma unroll
            for (int kx = 0; kx < 5; ++kx) {
                int ix = x + kx - 2;
                if ((unsigned)ix >= (unsigned)W) continue;
                acc = fmaf(ip[iy * W + ix], wk[ky * 5 + kx], acc);
            }
        }
        scale = s5[c]; bias = b5[c];
    }
    float v = fmaf(acc, scale, bias);
    cat[((size_t)b * Ctot + 2 * ch + c2) * HW + pix] = silu_act(v);
}

// CARAFE v4: zero-padded X tile in LDS; raw enc_px weights loaded per-thread
// (coalesced over l) and softmaxed IN REGISTERS (4 rp-groups x 25 taps).
// Block = (Y, 16-ch chunk, b); thread = (l = t&63, tc = t>>6); each thread
// computes 4 channels x 2x2 outputs at (oy=2Y+r, ox=2l+par), rp = r*2+par.
__global__ __launch_bounds__(256) void carafe_kernel(
        const float* __restrict__ X, const float* __restrict__ wraw,
        float* __restrict__ out) {
    const int H = 64, Wd = 64, C = 128, Ho = 128, Wo = 128, HW = H * Wd;
    int Y = blockIdx.x;           // 0..63
    int cchunk = blockIdx.y;      // 0..7
    int b = blockIdx.z;
    __shared__ float xs[16][5][68];     // zero-padded cols: col = ix+2, 21.8 KB
    int t = threadIdx.x;
    int c0 = cchunk * 16;
    const float* Xb = X + ((size_t)b * C + c0) * HW;
    for (int i = t; i < 16 * 5 * 68; i += 256) {
        int col = i % 68;
        int tmp = i / 68;
        int p = tmp % 5;
        int c = tmp / 5;
        int iy = Y + p - 2;
        int ix = col - 2;
        float v = 0.f;
        if ((unsigned)iy < (unsigned)H && (unsigned)ix < (unsigned)Wd)
            v = Xb[(size_t)c * HW + iy * Wd + ix];
        xs[c][p][col] = v;
    }
    int l = t & 63;
    int tc = t >> 6;
    // load raw pixel-shuffled weights for (Y, l): chW = j*4 + rp
    const float* wb = wraw + (size_t)b * 100 * HW + Y * Wd + l;
    float wreg[4][25];
#pragma unroll
    for (int rp = 0; rp < 4; ++rp)
#pragma unroll
        for (int j = 0; j < 25; ++j)
            wreg[rp][j] = wb[(size_t)(j * 4 + rp) * HW];
    // in-register softmax over the 25 taps, per rp
#pragma unroll
    for (int rp = 0; rp < 4; ++rp) {
        float m = -1e30f;
#pragma unroll
        for (int j = 0; j < 25; ++j) m = fmaxf(m, wreg[rp][j]);
        float s = 0.f;
#pragma unroll
        for (int j = 0; j < 25; ++j) { wreg[rp][j] = __expf(wreg[rp][j] - m); s += wreg[rp][j]; }
        float inv = 1.f / s;
#pragma unroll
        for (int j = 0; j < 25; ++j) wreg[rp][j] *= inv;
    }
    __syncthreads();

#pragma unroll
    for (int k = 0; k < 4; ++k) {
        int c = tc * 4 + k;
        float a00 = 0.f, a01 = 0.f, a10 = 0.f, a11 = 0.f;
#pragma unroll
        for (int p = 0; p < 5; ++p)
#pragma unroll
            for (int q = 0; q < 5; ++q) {
                float v = xs[c][p][l + q];
                int j = p * 5 + q;
                a00 = fmaf(wreg[0][j], v, a00);
                a01 = fmaf(wreg[1][j], v, a01);
                a10 = fmaf(wreg[2][j], v, a10);
                a11 = fmaf(wreg[3][j], v, a11);
            }
        size_t ob = (((size_t)b * C + (c0 + c)) * Ho + 2 * Y) * Wo + 2 * l;
        *reinterpret_cast<float2*>(&out[ob])      = make_float2(a00, a01);
        *reinterpret_cast<float2*>(&out[ob + Wo]) = make_float2(a10, a11);
    }
}

extern "C" void kernel_launch(void* const* d_in, const int* in_sizes, int n_in,
                              void* d_out, int out_size, void* d_ws, size_t ws_size,
                              hipStream_t stream) {
    const float* X          = (const float*)d_in[0];
    const float* comp_cv1_w = (const float*)d_in[1];
    const float* comp_cv1_s = (const float*)d_in[2];
    const float* comp_cv1_b = (const float*)d_in[3];
    const float* comp_dw3_w = (const float*)d_in[4];
    const float* comp_dw3_s = (const float*)d_in[5];
    const float* comp_dw3_b = (const float*)d_in[6];
    const float* comp_dw5_w = (const float*)d_in[7];
    const float* comp_dw5_s = (const float*)d_in[8];
    const float* comp_dw5_b = (const float*)d_in[9];
    const float* comp_px_w  = (const float*)d_in[10];
    const float* comp_px_s  = (const float*)d_in[11];
    const float* comp_px_b  = (const float*)d_in[12];
    const float* enc_cv1_w  = (const float*)d_in[13];
    const float* enc_cv1_s  = (const float*)d_in[14];
    const float* enc_cv1_b  = (const float*)d_in[15];
    const float* enc_dw3_w  = (const float*)d_in[16];
    const float* enc_dw3_s  = (const float*)d_in[17];
    const float* enc_dw3_b  = (const float*)d_in[18];
    const float* enc_dw5_w  = (const float*)d_in[19];
    const float* enc_dw5_s  = (const float*)d_in[20];
    const float* enc_dw5_b  = (const float*)d_in[21];
    const float* enc_px_w   = (const float*)d_in[22];
    const float* enc_px_s   = (const float*)d_in[23];
    const float* enc_px_b   = (const float*)d_in[24];
    float* out = (float*)d_out;

    const int B = 2, H = 64, W = 64, HW = H * W;
    float* cat_c  = (float*)d_ws;                      // [B, 64, HW]
    float* y_comp = cat_c  + (size_t)B * 64 * HW;      // [B, 64, HW]
    float* cat_e  = y_comp + (size_t)B * 64 * HW;      // [B,100, HW]
    float* wraw   = cat_e  + (size_t)B * 100 * HW;     // [B,100, HW]

    int pixBlocks = (B * HW + 255) / 256;   // 32

    // comp MSGConv
    pw_conv_silu<4, 128><<<dim3(pixBlocks, 8), 256, 0, stream>>>(
        X, HW, B, comp_cv1_w, comp_cv1_s, comp_cv1_b, cat_c, 64);
    {
        int n = B * 32 * HW;
        dw_conv_silu<<<(n + 255) / 256, 256, 0, stream>>>(
            cat_c, 16, H, W, 64, B,
            comp_dw3_w, comp_dw3_s, comp_dw3_b,
            comp_dw5_w, comp_dw5_s, comp_dw5_b);
    }
    pw_conv_silu<4, 64><<<dim3(pixBlocks, 16), 256, 0, stream>>>(
        cat_c, HW, B, comp_px_w, comp_px_s, comp_px_b, y_comp, 64);

    // enc MSGConv
    pw_conv_silu<5, 64><<<dim3(pixBlocks, 10), 256, 0, stream>>>(
        y_comp, HW, B, enc_cv1_w, enc_cv1_s, enc_cv1_b, cat_e, 100);
    {
        int n = B * 50 * HW;
        dw_conv_silu<<<(n + 255) / 256, 256, 0, stream>>>(
            cat_e, 25, H, W, 100, B,
            enc_dw3_w, enc_dw3_s, enc_dw3_b,
            enc_dw5_w, enc_dw5_s, enc_dw5_b);
    }
    pw_conv_silu<5, 100><<<dim3(pixBlocks, 20), 256, 0, stream>>>(
        cat_e, HW, B, enc_px_w, enc_px_s, enc_px_b, wraw, 100);

    // CARAFE reassembly (softmax fused, in-register)
    carafe_kernel<<<dim3(64, 8, B), 256, 0, stream>>>(X, wraw, out);
}

// Round 5
// 78.754 us; speedup vs baseline: 1.2202x; 1.0013x over previous
//
#include <hip/hip_runtime.h>
#include <math.h>

__device__ __forceinline__ float silu_act(float y) {
    return y / (1.f + __expf(-y));
}

// Pointwise 1x1 conv + scale/bias + SiLU. Compile-time Cin for full unroll.
template<int TC, int CIN>
__global__ void pw_conv_silu(const float* __restrict__ in, int HW, int B,
                             const float* __restrict__ w,
                             const float* __restrict__ sc, const float* __restrict__ bi,
                             float* __restrict__ out, int CoutStride) {
    int g = blockIdx.x * blockDim.x + threadIdx.x;
    if (g >= B * HW) return;
    int b = g / HW, pix = g - b * HW;
    int co0 = blockIdx.y * TC;
    float acc[TC];
#pragma unroll
    for (int j = 0; j < TC; ++j) acc[j] = 0.f;
    const float* ip = in + (size_t)b * CIN * HW + pix;
    const float* wp = w + (size_t)co0 * CIN;
#pragma unroll 8
    for (int ci = 0; ci < CIN; ++ci) {
        float v = ip[(size_t)ci * HW];
#pragma unroll
        for (int j = 0; j < TC; ++j)
            acc[j] = fmaf(v, wp[j * CIN + ci], acc[j]);
    }
#pragma unroll
    for (int j = 0; j < TC; ++j) {
        int co = co0 + j;
        float y = fmaf(acc[j], sc[co], bi[co]);
        out[((size_t)b * CoutStride + co) * HW + pix] = silu_act(y);
    }
}

// Fused depthwise 3x3 (channels [0,ch)) and 5x5 (channels [ch,2ch)) + SiLU.
__global__ void dw_conv_silu(float* __restrict__ cat, int ch, int H, int W, int Ctot, int B,
                             const float* __restrict__ w3, const float* __restrict__ s3,
                             const float* __restrict__ b3,
                             const float* __restrict__ w5, const float* __restrict__ s5,
                             const float* __restrict__ b5) {
    int HW = H * W;
    int idx = blockIdx.x * blockDim.x + threadIdx.x;
    int total = B * 2 * ch * HW;
    if (idx >= total) return;
    int pix = idx % HW;
    int t = idx / HW;
    int c2 = t % (2 * ch);
    int b = t / (2 * ch);
    int x = pix % W, y = pix / W;
    const float* ip = cat + ((size_t)b * Ctot + c2) * HW;
    float acc = 0.f, scale, bias;
    if (c2 < ch) {
        const float* wk = w3 + c2 * 9;
#pragma unroll
        for (int ky = 0; ky < 3; ++ky) {
            int iy = y + ky - 1;
            if ((unsigned)iy >= (unsigned)H) continue;
#pragma unroll
            for (int kx = 0; kx < 3; ++kx) {
                int ix = x + kx - 1;
                if ((unsigned)ix >= (unsigned)W) continue;
                acc = fmaf(ip[iy * W + ix], wk[ky * 3 + kx], acc);
            }
        }
        scale = s3[c2]; bias = b3[c2];
    } else {
        int c = c2 - ch;
        const float* wk = w5 + c * 25;
#pragma unroll
        for (int ky = 0; ky < 5; ++ky) {
            int iy = y + ky - 2;
            if ((unsigned)iy >= (unsigned)H) continue;
#pragma unroll
            for (int kx = 0; kx < 5; ++kx) {
                int ix = x + kx - 2;
                if ((unsigned)ix >= (unsigned)W) continue;
                acc = fmaf(ip[iy * W + ix], wk[ky * 5 + kx], acc);
            }
        }
        scale = s5[c]; bias = b5[c];
    }
    float v = fmaf(acc, scale, bias);
    cat[((size_t)b * Ctot + 2 * ch + c2) * HW + pix] = silu_act(v);
}

// CARAFE v4: zero-padded X tile in LDS; raw enc_px weights loaded per-thread
// (coalesced over l) and softmaxed IN REGISTERS (4 rp-groups x 25 taps).
// Block = (Y, 16-ch chunk, b); thread = (l = t&63, tc = t>>6); each thread
// computes 4 channels x 2x2 outputs at (oy=2Y+r, ox=2l+par), rp = r*2+par.
__global__ __launch_bounds__(256) void carafe_kernel(
        const float* __restrict__ X, const float* __restrict__ wraw,
        float* __restrict__ out) {
    const int H = 64, Wd = 64, C = 128, Ho = 128, Wo = 128, HW = H * Wd;
    int Y = blockIdx.x;           // 0..63
    int cchunk = blockIdx.y;      // 0..7
    int b = blockIdx.z;
    __shared__ float xs[16][5][68];     // zero-padded cols: col = ix+2, 21.8 KB
    int t = threadIdx.x;
    int c0 = cchunk * 16;
    const float* Xb = X + ((size_t)b * C + c0) * HW;
    for (int i = t; i < 16 * 5 * 68; i += 256) {
        int col = i % 68;
        int tmp = i / 68;
        int p = tmp % 5;
        int c = tmp / 5;
        int iy = Y + p - 2;
        int ix = col - 2;
        float v = 0.f;
        if ((unsigned)iy < (unsigned)H && (unsigned)ix < (unsigned)Wd)
            v = Xb[(size_t)c * HW + iy * Wd + ix];
        xs[c][p][col] = v;
    }
    int l = t & 63;
    int tc = t >> 6;
    // load raw pixel-shuffled weights for (Y, l): chW = j*4 + rp
    const float* wb = wraw + (size_t)b * 100 * HW + Y * Wd + l;
    float wreg[4][25];
#pragma unroll
    for (int rp = 0; rp < 4; ++rp)
#pragma unroll
        for (int j = 0; j < 25; ++j)
            wreg[rp][j] = wb[(size_t)(j * 4 + rp) * HW];
    // in-register softmax over the 25 taps, per rp
#pragma unroll
    for (int rp = 0; rp < 4; ++rp) {
        float m = -1e30f;
#pragma unroll
        for (int j = 0; j < 25; ++j) m = fmaxf(m, wreg[rp][j]);
        float s = 0.f;
#pragma unroll
        for (int j = 0; j < 25; ++j) { wreg[rp][j] = __expf(wreg[rp][j] - m); s += wreg[rp][j]; }
        float inv = 1.f / s;
#pragma unroll
        for (int j = 0; j < 25; ++j) wreg[rp][j] *= inv;
    }
    __syncthreads();

#pragma unroll
    for (int k = 0; k < 4; ++k) {
        int c = tc * 4 + k;
        float a00 = 0.f, a01 = 0.f, a10 = 0.f, a11 = 0.f;
#pragma unroll
        for (int p = 0; p < 5; ++p)
#pragma unroll
            for (int q = 0; q < 5; ++q) {
                float v = xs[c][p][l + q];
                int j = p * 5 + q;
                a00 = fmaf(wreg[0][j], v, a00);
                a01 = fmaf(wreg[1][j], v, a01);
                a10 = fmaf(wreg[2][j], v, a10);
                a11 = fmaf(wreg[3][j], v, a11);
            }
        size_t ob = (((size_t)b * C + (c0 + c)) * Ho + 2 * Y) * Wo + 2 * l;
        *reinterpret_cast<float2*>(&out[ob])      = make_float2(a00, a01);
        *reinterpret_cast<float2*>(&out[ob + Wo]) = make_float2(a10, a11);
    }
}

extern "C" void kernel_launch(void* const* d_in, const int* in_sizes, int n_in,
                              void* d_out, int out_size, void* d_ws, size_t ws_size,
                              hipStream_t stream) {
    const float* X          = (const float*)d_in[0];
    const float* comp_cv1_w = (const float*)d_in[1];
    const float* comp_cv1_s = (const float*)d_in[2];
    const float* comp_cv1_b = (const float*)d_in[3];
    const float* comp_dw3_w = (const float*)d_in[4];
    const float* comp_dw3_s = (const float*)d_in[5];
    const float* comp_dw3_b = (const float*)d_in[6];
    const float* comp_dw5_w = (const float*)d_in[7];
    const float* comp_dw5_s = (const float*)d_in[8];
    const float* comp_dw5_b = (const float*)d_in[9];
    const float* comp_px_w  = (const float*)d_in[10];
    const float* comp_px_s  = (const float*)d_in[11];
    const float* comp_px_b  = (const float*)d_in[12];
    const float* enc_cv1_w  = (const float*)d_in[13];
    const float* enc_cv1_s  = (const float*)d_in[14];
    const float* enc_cv1_b  = (const float*)d_in[15];
    const float* enc_dw3_w  = (const float*)d_in[16];
    const float* enc_dw3_s  = (const float*)d_in[17];
    const float* enc_dw3_b  = (const float*)d_in[18];
    const float* enc_dw5_w  = (const float*)d_in[19];
    const float* enc_dw5_s  = (const float*)d_in[20];
    const float* enc_dw5_b  = (const float*)d_in[21];
    const float* enc_px_w   = (const float*)d_in[22];
    const float* enc_px_s   = (const float*)d_in[23];
    const float* enc_px_b   = (const float*)d_in[24];
    float* out = (float*)d_out;

    const int B = 2, H = 64, W = 64, HW = H * W;
    float* cat_c  = (float*)d_ws;                      // [B, 64, HW]
    float* y_comp = cat_c  + (size_t)B * 64 * HW;      // [B, 64, HW]
    float* cat_e  = y_comp + (size_t)B * 64 * HW;      // [B,100, HW]
    float* wraw   = cat_e  + (size_t)B * 100 * HW;     // [B,100, HW]

    int pixBlocks = (B * HW + 255) / 256;   // 32

    // comp MSGConv
    pw_conv_silu<4, 128><<<dim3(pixBlocks, 8), 256, 0, stream>>>(
        X, HW, B, comp_cv1_w, comp_cv1_s, comp_cv1_b, cat_c, 64);
    {
        int n = B * 32 * HW;
        dw_conv_silu<<<(n + 255) / 256, 256, 0, stream>>>(
            cat_c, 16, H, W, 64, B,
            comp_dw3_w, comp_dw3_s, comp_dw3_b,
            comp_dw5_w, comp_dw5_s, comp_dw5_b);
    }
    pw_conv_silu<4, 64><<<dim3(pixBlocks, 16), 256, 0, stream>>>(
        cat_c, HW, B, comp_px_w, comp_px_s, comp_px_b, y_comp, 64);

    // enc MSGConv
    pw_conv_silu<5, 64><<<dim3(pixBlocks, 10), 256, 0, stream>>>(
        y_comp, HW, B, enc_cv1_w, enc_cv1_s, enc_cv1_b, cat_e, 100);
    {
        int n = B * 50 * HW;
        dw_conv_silu<<<(n + 255) / 256, 256, 0, stream>>>(
            cat_e, 25, H, W, 100, B,
            enc_dw3_w, enc_dw3_s, enc_dw3_b,
            enc_dw5_w, enc_dw5_s, enc_dw5_b);
    }
    pw_conv_silu<5, 100><<<dim3(pixBlocks, 20), 256, 0, stream>>>(
        cat_e, HW, B, enc_px_w, enc_px_s, enc_px_b, wraw, 100);

    // CARAFE reassembly (softmax fused, in-register)
    carafe_kernel<<<dim3(64, 8, B), 256, 0, stream>>>(X, wraw, out);
}